// Round 1
// baseline (97.779 us; speedup 1.0000x reference)
//
#include <hip/hip_runtime.h>
#include <math.h>

typedef unsigned long long u64;

// gumbel from uniform, in double to match numpy-f64 reference decisions
__device__ __forceinline__ double gumbel(double u) {
  u = fmin(fmax(u, 1e-10), 1.0 - 1e-10);
  return -log(-log(u));
}

// r = m[lane] ? tval : fval  -- mask held in an SGPR pair, one v_cndmask for 64 lanes
__device__ __forceinline__ float csel(u64 m, float tval, float fval) {
  float r;
  asm("v_cndmask_b32 %0, %1, %2, %3" : "=v"(r) : "v"(fval), "v"(tval), "s"(m));
  return r;
}

// One wave per (layer, o-group, i). Lane l = output o = g*64+l.
// maskT0[g*512 + i] bit l = edge(o=g*64+l, i) selected (layer0)
// maskT1[g*256 + i] bit l = edge(o=g*64+l, i) selected (layer1)
__global__ __launch_bounds__(256, 4) void masks_kernel(
    const float* __restrict__ l0, const float* __restrict__ u0,
    const float* __restrict__ l1, const float* __restrict__ u1,
    u64* __restrict__ mT0, u64* __restrict__ mT1) {
  int t = blockIdx.x * 256 + threadIdx.x;
  int W = t >> 6;          // wave id, 0..4095
  int lane = t & 63;
  const float* lp;
  const float* up;
  u64* mp;
  int nin, g, i;
  if (W < 2048) {          // layer 0: 4 groups x 512 inputs
    g = W >> 9; i = W & 511;
    lp = l0; up = u0; nin = 512;
    mp = mT0 + (g << 9) + i;
  } else {                 // layer 1: 8 groups x 256 inputs
    int W1 = W - 2048;
    g = W1 >> 8; i = W1 & 255;
    lp = l1; up = u1; nin = 256;
    mp = mT1 + (g << 8) + i;
  }
  int o = (g << 6) + lane;
  int idx = (o * nin + i) << 1;   // (o, i, e=0)
  double va = (double)lp[idx]     + gumbel((double)up[idx]);
  double vb = (double)lp[idx + 1] + gumbel((double)up[idx + 1]);
  // argmax picks first index on tie -> edge selected iff strictly greater
  u64 m = __ballot(vb > va);
  if (lane == 0) *mp = m;
}

// One block per batch row. Phase 1: h[o] = min over selected x (split-K by 2 waves/group).
// Phase 2: out[o] = max over selected h. h lives only in LDS.
__global__ __launch_bounds__(512, 8) void fused_kernel(
    const float* __restrict__ x, const u64* __restrict__ mT0,
    const u64* __restrict__ mT1, float* __restrict__ out) {
  __shared__ float sx[512];
  __shared__ float sh[256];
  __shared__ float spart[8][64];
  const int tid = threadIdx.x;
  const int b = blockIdx.x;
  sx[tid] = x[b * 512 + tid];
  __syncthreads();
  const int w = __builtin_amdgcn_readfirstlane(tid >> 6);  // force wave-uniform
  const int lane = tid & 63;

  // ---- phase 1: layer 0 (min over selected x, else 1.0) ----
  {
    int g = w >> 1, half = w & 1;
    const u64* __restrict__ mrow = mT0 + (g << 9) + (half << 8);
    const float* xs = sx + (half << 8);
    float acc = 1.0f;
#pragma unroll 8
    for (int i = 0; i < 256; i += 2) {
      float t0 = csel(mrow[i],     xs[i],     1.0f);
      float t1 = csel(mrow[i + 1], xs[i + 1], 1.0f);
      acc = fminf(acc, fminf(t0, t1));   // v_min3_f32
    }
    spart[w][lane] = acc;
  }
  __syncthreads();
  if (w < 4) sh[(w << 6) + lane] = fminf(spart[2 * w][lane], spart[2 * w + 1][lane]);
  __syncthreads();

  // ---- phase 2: layer 1 (max over selected h, else 0.0) ----
  {
    const u64* __restrict__ mrow = mT1 + (w << 8);
    float acc = 0.0f;
#pragma unroll 8
    for (int i = 0; i < 256; i += 2) {
      float t0 = csel(mrow[i],     sh[i],     0.0f);
      float t1 = csel(mrow[i + 1], sh[i + 1], 0.0f);
      acc = fmaxf(acc, fmaxf(t0, t1));   // v_max3_f32
    }
    out[b * 512 + (w << 6) + lane] = acc;
  }
}

extern "C" void kernel_launch(void* const* d_in, const int* in_sizes, int n_in,
                              void* d_out, int out_size, void* d_ws, size_t ws_size,
                              hipStream_t stream) {
  const float* x  = (const float*)d_in[0];
  const float* l0 = (const float*)d_in[1];
  const float* u0 = (const float*)d_in[2];
  const float* l1 = (const float*)d_in[3];
  const float* u1 = (const float*)d_in[4];
  u64* mT0 = (u64*)d_ws;        // 2048 words, 16 KB
  u64* mT1 = mT0 + 2048;        // 2048 words, 16 KB
  float* out = (float*)d_out;

  hipLaunchKernelGGL(masks_kernel, dim3(1024), dim3(256), 0, stream,
                     l0, u0, l1, u1, mT0, mT1);
  hipLaunchKernelGGL(fused_kernel, dim3(1024), dim3(512), 0, stream,
                     x, mT0, mT1, out);
}

// Round 2
// 89.949 us; speedup vs baseline: 1.0870x; 1.0870x over previous
//
#include <hip/hip_runtime.h>
#include <math.h>

typedef unsigned long long u64;

// gumbel from uniform, in double to match f64 reference decisions (bit-identical
// to the passing R1 version -- do not change)
__device__ __forceinline__ double gumbel(double u) {
  u = fmin(fmax(u, 1e-10), 1.0 - 1e-10);
  return -log(-log(u));
}

// r = m[lane] ? tval : fval  -- mask held in an SGPR pair, one v_cndmask for 64 lanes
__device__ __forceinline__ float csel(u64 m, float tval, float fval) {
  float r;
  asm("v_cndmask_b32 %0, %1, %2, %3" : "=v"(r) : "v"(fval), "v"(tval), "s"(m));
  return r;
}

// One wave per (layer, o-group, i-pair). Lane l = output o = g*64+l.
// Each thread decides edges for (o, i) and (o, i+1) -> 2 ballots -> 2 mask words.
// maskT0[g*512 + i] bit l = edge(o=g*64+l, i) selected (layer0)
// maskT1[g*256 + i] bit l = edge(o=g*64+l, i) selected (layer1)
__global__ __launch_bounds__(256, 4) void masks_kernel(
    const float* __restrict__ l0, const float* __restrict__ u0,
    const float* __restrict__ l1, const float* __restrict__ u1,
    u64* __restrict__ mT0, u64* __restrict__ mT1) {
  int t = blockIdx.x * 256 + threadIdx.x;
  int W = t >> 6;          // wave id, 0..2047
  int lane = t & 63;
  const float* lp;
  const float* up;
  u64* mp;
  int nin, g, ip;          // ip = i/2 (pair index)
  if (W < 1024) {          // layer 0: 4 groups x 256 i-pairs
    g = W >> 8; ip = W & 255;
    lp = l0; up = u0; nin = 512;
    mp = mT0 + (g << 9) + (ip << 1);
  } else {                 // layer 1: 8 groups x 128 i-pairs
    int W1 = W - 1024;
    g = W1 >> 7; ip = W1 & 127;
    lp = l1; up = u1; nin = 256;
    mp = mT1 + (g << 8) + (ip << 1);
  }
  int o = (g << 6) + lane;
  int idx = (o * nin + (ip << 1)) << 1;   // (o, i, e=0), 16B-aligned
  float4 lv = *(const float4*)(lp + idx); // l[o,i,0..1], l[o,i+1,0..1]
  float4 uv = *(const float4*)(up + idx);
  double a0 = (double)lv.x + gumbel((double)uv.x);
  double b0 = (double)lv.y + gumbel((double)uv.y);
  double a1 = (double)lv.z + gumbel((double)uv.z);
  double b1 = (double)lv.w + gumbel((double)uv.w);
  // argmax picks first index on tie -> edge selected iff strictly greater
  u64 m0 = __ballot(b0 > a0);
  u64 m1 = __ballot(b1 > a1);
  if (lane == 0) { mp[0] = m0; mp[1] = m1; }
}

// One block per batch row. Phase 1: h[o] = min over selected x (split-K by 2 waves/group).
// Phase 2: out[o] = max over selected h. h lives only in LDS.
__global__ __launch_bounds__(512, 8) void fused_kernel(
    const float* __restrict__ x, const u64* __restrict__ mT0,
    const u64* __restrict__ mT1, float* __restrict__ out) {
  __shared__ float sx[512];
  __shared__ float sh[256];
  __shared__ float spart[8][64];
  const int tid = threadIdx.x;
  const int b = blockIdx.x;
  sx[tid] = x[b * 512 + tid];
  __syncthreads();
  const int w = __builtin_amdgcn_readfirstlane(tid >> 6);  // force wave-uniform
  const int lane = tid & 63;

  // ---- phase 1: layer 0 (min over selected x, else 1.0) ----
  {
    int g = w >> 1, half = w & 1;
    const u64* __restrict__ mrow = mT0 + (g << 9) + (half << 8);
    const float4* xs4 = (const float4*)(sx + (half << 8));
    float acc0 = 1.0f, acc1 = 1.0f;
#pragma unroll 4
    for (int i = 0; i < 256; i += 4) {
      float4 xv = xs4[i >> 2];                  // ds_read_b128 broadcast
      u64 m0 = mrow[i], m1 = mrow[i + 1];       // contiguous -> s_load_dwordx8
      u64 m2 = mrow[i + 2], m3 = mrow[i + 3];
      float t0 = csel(m0, xv.x, 1.0f);
      float t1 = csel(m1, xv.y, 1.0f);
      float t2 = csel(m2, xv.z, 1.0f);
      float t3 = csel(m3, xv.w, 1.0f);
      acc0 = fminf(acc0, fminf(t0, t1));        // v_min3_f32, chain 0
      acc1 = fminf(acc1, fminf(t2, t3));        // v_min3_f32, chain 1
    }
    spart[w][lane] = fminf(acc0, acc1);
  }
  __syncthreads();
  if (w < 4) sh[(w << 6) + lane] = fminf(spart[2 * w][lane], spart[2 * w + 1][lane]);
  __syncthreads();

  // ---- phase 2: layer 1 (max over selected h, else 0.0) ----
  {
    const u64* __restrict__ mrow = mT1 + (w << 8);
    const float4* hs4 = (const float4*)sh;
    float acc0 = 0.0f, acc1 = 0.0f;
#pragma unroll 4
    for (int i = 0; i < 256; i += 4) {
      float4 hv = hs4[i >> 2];                  // ds_read_b128 broadcast
      u64 m0 = mrow[i], m1 = mrow[i + 1];
      u64 m2 = mrow[i + 2], m3 = mrow[i + 3];
      float t0 = csel(m0, hv.x, 0.0f);
      float t1 = csel(m1, hv.y, 0.0f);
      float t2 = csel(m2, hv.z, 0.0f);
      float t3 = csel(m3, hv.w, 0.0f);
      acc0 = fmaxf(acc0, fmaxf(t0, t1));        // v_max3_f32, chain 0
      acc1 = fmaxf(acc1, fmaxf(t2, t3));        // v_max3_f32, chain 1
    }
    out[b * 512 + (w << 6) + lane] = fmaxf(acc0, acc1);
  }
}

extern "C" void kernel_launch(void* const* d_in, const int* in_sizes, int n_in,
                              void* d_out, int out_size, void* d_ws, size_t ws_size,
                              hipStream_t stream) {
  const float* x  = (const float*)d_in[0];
  const float* l0 = (const float*)d_in[1];
  const float* u0 = (const float*)d_in[2];
  const float* l1 = (const float*)d_in[3];
  const float* u1 = (const float*)d_in[4];
  u64* mT0 = (u64*)d_ws;        // 2048 words, 16 KB
  u64* mT1 = mT0 + 2048;        // 2048 words, 16 KB
  float* out = (float*)d_out;

  hipLaunchKernelGGL(masks_kernel, dim3(512), dim3(256), 0, stream,
                     l0, u0, l1, u1, mT0, mT1);
  hipLaunchKernelGGL(fused_kernel, dim3(1024), dim3(512), 0, stream,
                     x, mT0, mT1, out);
}

// Round 3
// 87.336 us; speedup vs baseline: 1.1196x; 1.0299x over previous
//
#include <hip/hip_runtime.h>
#include <math.h>

typedef unsigned long long u64;

// gumbel from uniform, in double -- fallback path only (logits != 0), matches
// f64 reference decisions bit-exactly
__device__ __forceinline__ double gumbel(double u) {
  u = fmin(fmax(u, 1e-10), 1.0 - 1e-10);
  return -log(-log(u));
}

// r = m[lane] ? tval : fval  -- mask held in an SGPR pair, one v_cndmask for 64 lanes
__device__ __forceinline__ float csel(u64 m, float tval, float fval) {
  float r;
  asm("v_cndmask_b32 %0, %1, %2, %3" : "=v"(r) : "v"(fval), "v"(tval), "s"(m));
  return r;
}

// One wave per (layer, o-group, i-pair). Lane l = output o = g*64+l.
// Each thread decides edges for (o, i) and (o, i+1) -> 2 ballots -> 2 mask words.
// FAST PATH: logits are identically zero in this problem, and gumbel() is
// strictly monotone increasing in u, so argmax(logits+gumbel(u)) == argmax(u).
// The raw u compare is bit-exact vs the reference on the 2^-24 uniform grid
// (clip corner at u==0 included; ties -> no edge, both ways). f64 fallback
// kept for nonzero logits (never taken here, wave-uniform branch).
__global__ __launch_bounds__(256, 4) void masks_kernel(
    const float* __restrict__ l0, const float* __restrict__ u0,
    const float* __restrict__ l1, const float* __restrict__ u1,
    u64* __restrict__ mT0, u64* __restrict__ mT1) {
  int t = blockIdx.x * 256 + threadIdx.x;
  int W = t >> 6;          // wave id, 0..2047
  int lane = t & 63;
  const float* lp;
  const float* up;
  u64* mp;
  int nin, g, ip;          // ip = i/2 (pair index)
  if (W < 1024) {          // layer 0: 4 groups x 256 i-pairs
    g = W >> 8; ip = W & 255;
    lp = l0; up = u0; nin = 512;
    mp = mT0 + (g << 9) + (ip << 1);
  } else {                 // layer 1: 8 groups x 128 i-pairs
    int W1 = W - 1024;
    g = W1 >> 7; ip = W1 & 127;
    lp = l1; up = u1; nin = 256;
    mp = mT1 + (g << 8) + (ip << 1);
  }
  int o = (g << 6) + lane;
  int idx = (o * nin + (ip << 1)) << 1;   // (o, i, e=0), 16B-aligned
  float4 lv = *(const float4*)(lp + idx); // l[o,i,0..1], l[o,i+1,0..1]
  float4 uv = *(const float4*)(up + idx);
  bool d0, d1;
  if (lv.x == 0.0f && lv.y == 0.0f && lv.z == 0.0f && lv.w == 0.0f) {
    // logits zero: compare raw uniforms (monotone-exact)
    d0 = uv.y > uv.x;
    d1 = uv.w > uv.z;
  } else {
    double a0 = (double)lv.x + gumbel((double)uv.x);
    double b0 = (double)lv.y + gumbel((double)uv.y);
    double a1 = (double)lv.z + gumbel((double)uv.z);
    double b1 = (double)lv.w + gumbel((double)uv.w);
    d0 = b0 > a0;
    d1 = b1 > a1;
  }
  // argmax picks first index on tie -> edge selected iff strictly greater
  u64 m0 = __ballot(d0);
  u64 m1 = __ballot(d1);
  if (lane == 0) {
    ulonglong2 v;
    v.x = m0; v.y = m1;
    *(ulonglong2*)mp = v;   // one 16B store
  }
}

// One block per batch row. Phase 1: h[o] = min over selected x (split-K by 2 waves/group).
// Phase 2: out[o] = max over selected h. h lives only in LDS.
__global__ __launch_bounds__(512, 8) void fused_kernel(
    const float* __restrict__ x, const u64* __restrict__ mT0,
    const u64* __restrict__ mT1, float* __restrict__ out) {
  __shared__ float sx[512];
  __shared__ float sh[256];
  __shared__ float spart[8][64];
  const int tid = threadIdx.x;
  const int b = blockIdx.x;
  sx[tid] = x[b * 512 + tid];
  __syncthreads();
  const int w = __builtin_amdgcn_readfirstlane(tid >> 6);  // force wave-uniform
  const int lane = tid & 63;

  // ---- phase 1: layer 0 (min over selected x, else 1.0) ----
  {
    int g = w >> 1, half = w & 1;
    const u64* __restrict__ mrow = mT0 + (g << 9) + (half << 8);
    const float4* xs4 = (const float4*)(sx + (half << 8));
    float acc0 = 1.0f, acc1 = 1.0f;
#pragma unroll 8
    for (int i = 0; i < 256; i += 4) {
      float4 xv = xs4[i >> 2];                  // ds_read_b128 broadcast
      u64 m0 = mrow[i], m1 = mrow[i + 1];       // contiguous -> scalar loads
      u64 m2 = mrow[i + 2], m3 = mrow[i + 3];
      float t0 = csel(m0, xv.x, 1.0f);
      float t1 = csel(m1, xv.y, 1.0f);
      float t2 = csel(m2, xv.z, 1.0f);
      float t3 = csel(m3, xv.w, 1.0f);
      acc0 = fminf(acc0, fminf(t0, t1));        // v_min3_f32, chain 0
      acc1 = fminf(acc1, fminf(t2, t3));        // v_min3_f32, chain 1
    }
    spart[w][lane] = fminf(acc0, acc1);
  }
  __syncthreads();
  if (w < 4) sh[(w << 6) + lane] = fminf(spart[2 * w][lane], spart[2 * w + 1][lane]);
  __syncthreads();

  // ---- phase 2: layer 1 (max over selected h, else 0.0) ----
  {
    const u64* __restrict__ mrow = mT1 + (w << 8);
    const float4* hs4 = (const float4*)sh;
    float acc0 = 0.0f, acc1 = 0.0f;
#pragma unroll 8
    for (int i = 0; i < 256; i += 4) {
      float4 hv = hs4[i >> 2];                  // ds_read_b128 broadcast
      u64 m0 = mrow[i], m1 = mrow[i + 1];
      u64 m2 = mrow[i + 2], m3 = mrow[i + 3];
      float t0 = csel(m0, hv.x, 0.0f);
      float t1 = csel(m1, hv.y, 0.0f);
      float t2 = csel(m2, hv.z, 0.0f);
      float t3 = csel(m3, hv.w, 0.0f);
      acc0 = fmaxf(acc0, fmaxf(t0, t1));        // v_max3_f32, chain 0
      acc1 = fmaxf(acc1, fmaxf(t2, t3));        // v_max3_f32, chain 1
    }
    out[b * 512 + (w << 6) + lane] = fmaxf(acc0, acc1);
  }
}

extern "C" void kernel_launch(void* const* d_in, const int* in_sizes, int n_in,
                              void* d_out, int out_size, void* d_ws, size_t ws_size,
                              hipStream_t stream) {
  const float* x  = (const float*)d_in[0];
  const float* l0 = (const float*)d_in[1];
  const float* u0 = (const float*)d_in[2];
  const float* l1 = (const float*)d_in[3];
  const float* u1 = (const float*)d_in[4];
  u64* mT0 = (u64*)d_ws;        // 2048 words, 16 KB
  u64* mT1 = mT0 + 2048;        // 2048 words, 16 KB
  float* out = (float*)d_out;

  hipLaunchKernelGGL(masks_kernel, dim3(512), dim3(256), 0, stream,
                     l0, u0, l1, u1, mT0, mT1);
  hipLaunchKernelGGL(fused_kernel, dim3(1024), dim3(512), 0, stream,
                     x, mT0, mT1, out);
}

// Round 4
// 85.993 us; speedup vs baseline: 1.1370x; 1.0156x over previous
//
#include <hip/hip_runtime.h>
#include <hip/hip_fp16.h>
#include <math.h>

typedef unsigned long long u64;
typedef unsigned int uint32;

// gumbel from uniform, in double -- fallback path only (logits != 0), matches
// f64 reference decisions bit-exactly
__device__ __forceinline__ double gumbel(double u) {
  u = fmin(fmax(u, 1e-10), 1.0 - 1e-10);
  return -log(-log(u));
}

// r = m[lane] ? tval : fval  -- mask in an SGPR pair, one v_cndmask selects a
// packed half2 (2 batch rows) per lane: 2 cells per instruction.
__device__ __forceinline__ uint32 csel2(u64 m, uint32 tval, uint32 fval) {
  uint32 r;
  asm("v_cndmask_b32 %0, %1, %2, %3" : "=v"(r) : "v"(fval), "v"(tval), "s"(m));
  return r;
}
__device__ __forceinline__ uint32 pkmin(uint32 a, uint32 b) {
  uint32 r;
  asm("v_pk_min_f16 %0, %1, %2" : "=v"(r) : "v"(a), "v"(b));
  return r;
}
__device__ __forceinline__ uint32 pkmax(uint32 a, uint32 b) {
  uint32 r;
  asm("v_pk_max_f16 %0, %1, %2" : "=v"(r) : "v"(a), "v"(b));
  return r;
}

#define ONE2 0x3C003C00u  // packed half2 {1.0, 1.0}

// One wave per (layer, o-group, i-pair). Lane l = output o = g*64+l.
// FAST PATH: logits are identically zero here and gumbel() is strictly
// monotone in u, so argmax(logits+gumbel(u)) == argmax(u) -- bit-exact.
// f64 fallback kept for nonzero logits (never taken, wave-uniform branch).
__global__ __launch_bounds__(256, 4) void masks_kernel(
    const float* __restrict__ l0, const float* __restrict__ u0,
    const float* __restrict__ l1, const float* __restrict__ u1,
    u64* __restrict__ mT0, u64* __restrict__ mT1) {
  int t = blockIdx.x * 256 + threadIdx.x;
  int W = t >> 6;          // wave id, 0..2047
  int lane = t & 63;
  const float* lp;
  const float* up;
  u64* mp;
  int nin, g, ip;          // ip = i/2 (pair index)
  if (W < 1024) {          // layer 0: 4 groups x 256 i-pairs
    g = W >> 8; ip = W & 255;
    lp = l0; up = u0; nin = 512;
    mp = mT0 + (g << 9) + (ip << 1);
  } else {                 // layer 1: 8 groups x 128 i-pairs
    int W1 = W - 1024;
    g = W1 >> 7; ip = W1 & 127;
    lp = l1; up = u1; nin = 256;
    mp = mT1 + (g << 8) + (ip << 1);
  }
  int o = (g << 6) + lane;
  int idx = (o * nin + (ip << 1)) << 1;   // (o, i, e=0), 16B-aligned
  float4 lv = *(const float4*)(lp + idx);
  float4 uv = *(const float4*)(up + idx);
  bool d0, d1;
  if (lv.x == 0.0f && lv.y == 0.0f && lv.z == 0.0f && lv.w == 0.0f) {
    d0 = uv.y > uv.x;     // logits zero: raw-uniform compare (monotone-exact)
    d1 = uv.w > uv.z;
  } else {
    double a0 = (double)lv.x + gumbel((double)uv.x);
    double b0 = (double)lv.y + gumbel((double)uv.y);
    double a1 = (double)lv.z + gumbel((double)uv.z);
    double b1 = (double)lv.w + gumbel((double)uv.w);
    d0 = b0 > a0;
    d1 = b1 > a1;
  }
  u64 m0 = __ballot(d0);
  u64 m1 = __ballot(d1);
  if (lane == 0) {
    ulonglong2 v; v.x = m0; v.y = m1;
    *(ulonglong2*)mp = v;   // one 16B store
  }
}

// One block per ROW PAIR (b0=2*bid, b1=b0+1), cells packed as half2 {b0,b1}.
// Phase 1: h[o] = min over selected x (split-K by 2 waves/group).
// Phase 2: out[o] = max over selected h. h lives only in LDS (f16, so phase 2
// adds no rounding error beyond the single f16 quantization of x: <=2^-12).
__global__ __launch_bounds__(512, 8) void fused_kernel(
    const float* __restrict__ x, const u64* __restrict__ mT0,
    const u64* __restrict__ mT1, float* __restrict__ out) {
  __shared__ uint32 sxp[512];       // packed half2 x for both rows
  __shared__ uint32 shp[256];       // packed half2 h
  __shared__ uint32 spart[8][64];
  const int tid = threadIdx.x;
  const int b0 = blockIdx.x * 2;
  {
    float f0 = x[b0 * 512 + tid];
    float f1 = x[b0 * 512 + 512 + tid];
    __half2 p = __floats2half2_rn(f0, f1);   // RNE: err <= 2^-12
    sxp[tid] = *(uint32*)&p;
  }
  __syncthreads();
  const int w = __builtin_amdgcn_readfirstlane(tid >> 6);  // wave-uniform
  const int lane = tid & 63;

  // ---- phase 1: layer 0 (min over selected x, else 1.0) ----
  {
    int g = w >> 1, half = w & 1;
    const u64* __restrict__ mrow = mT0 + (g << 9) + (half << 8);
    const uint32* xs = sxp + (half << 8);
    uint32 acc0 = ONE2, acc1 = ONE2;
#pragma unroll 8
    for (int i = 0; i < 256; i += 4) {
      uint4 xv = *(const uint4*)(xs + i);       // ds_read_b128 broadcast: 4i x 2rows
      u64 m0 = mrow[i], m1 = mrow[i + 1];
      u64 m2 = mrow[i + 2], m3 = mrow[i + 3];
      uint32 t0 = csel2(m0, xv.x, ONE2);
      uint32 t1 = csel2(m1, xv.y, ONE2);
      uint32 t2 = csel2(m2, xv.z, ONE2);
      uint32 t3 = csel2(m3, xv.w, ONE2);
      acc0 = pkmin(acc0, pkmin(t0, t1));        // chain 0
      acc1 = pkmin(acc1, pkmin(t2, t3));        // chain 1
    }
    spart[w][lane] = pkmin(acc0, acc1);
  }
  __syncthreads();
  if (w < 4) shp[(w << 6) + lane] = pkmin(spart[2 * w][lane], spart[2 * w + 1][lane]);
  __syncthreads();

  // ---- phase 2: layer 1 (max over selected h, else 0.0) ----
  {
    const u64* __restrict__ mrow = mT1 + (w << 8);
    uint32 acc0 = 0u, acc1 = 0u;                // packed half2 {0,0}
#pragma unroll 8
    for (int i = 0; i < 256; i += 4) {
      uint4 hv = *(const uint4*)(shp + i);      // ds_read_b128 broadcast
      u64 m0 = mrow[i], m1 = mrow[i + 1];
      u64 m2 = mrow[i + 2], m3 = mrow[i + 3];
      uint32 t0 = csel2(m0, hv.x, 0u);
      uint32 t1 = csel2(m1, hv.y, 0u);
      uint32 t2 = csel2(m2, hv.z, 0u);
      uint32 t3 = csel2(m3, hv.w, 0u);
      acc0 = pkmax(acc0, pkmax(t0, t1));        // chain 0
      acc1 = pkmax(acc1, pkmax(t2, t3));        // chain 1
    }
    uint32 acc = pkmax(acc0, acc1);
    __half2 hh = *(__half2*)&acc;
    int o = (w << 6) + lane;
    out[b0 * 512 + o]       = __low2float(hh);   // row b0
    out[b0 * 512 + 512 + o] = __high2float(hh);  // row b1
  }
}

extern "C" void kernel_launch(void* const* d_in, const int* in_sizes, int n_in,
                              void* d_out, int out_size, void* d_ws, size_t ws_size,
                              hipStream_t stream) {
  const float* x  = (const float*)d_in[0];
  const float* l0 = (const float*)d_in[1];
  const float* u0 = (const float*)d_in[2];
  const float* l1 = (const float*)d_in[3];
  const float* u1 = (const float*)d_in[4];
  u64* mT0 = (u64*)d_ws;        // 2048 words, 16 KB
  u64* mT1 = mT0 + 2048;        // 2048 words, 16 KB
  float* out = (float*)d_out;

  hipLaunchKernelGGL(masks_kernel, dim3(512), dim3(256), 0, stream,
                     l0, u0, l1, u1, mT0, mT1);
  hipLaunchKernelGGL(fused_kernel, dim3(512), dim3(512), 0, stream,
                     x, mT0, mT1, out);
}